// Round 5
// baseline (454.953 us; speedup 1.0000x reference)
//
#include <hip/hip_runtime.h>

#define H 512
#define W 960
#define OH 508
#define OW 956
#define NIMG 48

#define RH 32                       // output rows per wave
#define WAVES_PER_BLOCK 4
#define ROWS_PER_BLOCK (RH * WAVES_PER_BLOCK)   // 128
#define CW 4                        // output cols per thread
#define STRIPW (64 * CW)            // 256 output cols per wave-strip
#define KK 12                       // 12 x 3-phase body = 36 input rows (compile-time)

typedef float f32x4 __attribute__((ext_vector_type(4)));

// Issue the 4 global loads for input row (h0+KV), clamped, into 4 named
// float4 regs. Loads are issued AFTER the phase that consumed the buffer,
// so rows k+1..k+2 (and this re-issue) stay in flight under compute —
// per-wave MLP. Round-4 lesson: duration was pinned at 108us across
// VALU 44->30% and 3->6 waves/SIMD; the limiter is load latency with ~one
// batch in flight per CU. This keeps ~6KB/wave outstanding continuously.
#define LOADROW(KV, XA,XB,YA,YB) \
{ \
    const int r_ = h0 + (KV); \
    const int rl_ = r_ < H ? r_ : (H - 1); \
    const float4* px_ = (const float4*)(xi + (size_t)rl_ * W + cbl); \
    const float4* py_ = (const float4*)(yi + (size_t)rl_ * W + cbl); \
    XA = px_[0]; XB = px_[1]; \
    YA = py_[0]; YB = py_[1]; \
}

// One pipeline phase: consume buffered input row (wave-local index KV),
// update histories. ALL array args are distinct named locals with
// compile-time indices only — rotation is SSA renaming, nothing can fall
// to scratch (round-3 lesson: WRITE_SIZE 92->639MB at VGPR=64 is the
// demotion signature).
#define PHASE(KV, XA,XB,YA,YB, HX2,HY2, HX1,HY1, HXW,HYW, XC1,YC1, XCW,YCW, \
              HA2,HB2,HC2, HA1,HB1,HC1, HAW,HBW,HCW, MIX,MIY, MOX,MOY) \
{ \
    const int k_ = (KV); \
    float xc_[8] = {XA.x, XA.y, XA.z, XA.w, XB.x, XB.y, XB.z, XB.w}; \
    float yc_[8] = {YA.x, YA.y, YA.z, YA.w, YB.x, YB.y, YB.z, YB.w}; \
    _Pragma("unroll") \
    for (int q = 0; q < 6; ++q) { \
        HXW[q] = xc_[q] + xc_[q + 1] + xc_[q + 2]; \
        HYW[q] = yc_[q] + yc_[q + 1] + yc_[q + 2]; \
        XCW[q] = xc_[q + 1]; \
        YCW[q] = yc_[q + 1]; \
    } \
    if (k_ >= 2) { \
        float a6_[6], b6_[6], c6_[6]; \
        _Pragma("unroll") \
        for (int q = 0; q < 6; ++q) { \
            MOX[q] = (HX2[q] + HX1[q] + HXW[q]) * inv9; \
            MOY[q] = (HY2[q] + HY1[q] + HYW[q]) * inv9; \
            float dx_ = XC1[q] - MOX[q]; \
            float dy_ = YC1[q] - MOY[q]; \
            a6_[q] = dx_ * dx_; \
            b6_[q] = dy_ * dy_; \
            c6_[q] = dx_ * dy_; \
        } \
        float ha_[4], hb_[4], hc_[4]; \
        _Pragma("unroll") \
        for (int w = 0; w < 4; ++w) { \
            ha_[w] = a6_[w] + a6_[w + 1] + a6_[w + 2]; \
            hb_[w] = b6_[w] + b6_[w + 1] + b6_[w + 2]; \
            hc_[w] = c6_[w] + c6_[w + 1] + c6_[w + 2]; \
        } \
        if (k_ >= 4) { \
            const int h_ = h0 + k_ - 4; \
            float ov_[4]; \
            _Pragma("unroll") \
            for (int w = 0; w < 4; ++w) { \
                float sigx_  = (HA2[w] + HA1[w] + ha_[w]) * inv9; \
                float sigy_  = (HB2[w] + HB1[w] + hb_[w]) * inv9; \
                float sigxy_ = (HC2[w] + HC1[w] + hc_[w]) * inv9; \
                float mx_ = MIX[w + 1]; \
                float my_ = MIY[w + 1]; \
                float n_ = (2.f * mx_ * my_ + C1v) * (2.f * sigxy_ + C2v); \
                float d_ = (mx_ * mx_ + my_ * my_ + C1v) * (sigx_ + sigy_ + C2v); \
                float v_ = 1.f - n_ * __builtin_amdgcn_rcpf(d_); \
                ov_[w] = fminf(fmaxf(v_, 0.f), 2.f); \
            } \
            if (col_ok && h_ < OH) { \
                f32x4 o_ = {ov_[0], ov_[1], ov_[2], ov_[3]}; \
                __builtin_nontemporal_store(o_, (f32x4*)(oi + (size_t)h_ * OW + cb)); \
            } \
        } \
        _Pragma("unroll") \
        for (int w = 0; w < 4; ++w) { \
            HAW[w] = ha_[w]; HBW[w] = hb_[w]; HCW[w] = hc_[w]; \
        } \
    } \
}

// Register-resident sliding-window SSIM, 3-phase hand-rotated pipeline with
// 3 rotating row buffers (A/B/C) for deep per-wave load MLP.
// Thread = 4 output cols; wave = 256-col strip x 32 rows; no LDS, no barriers.
// __launch_bounds__(256,3): grid supplies exactly 3 blocks/CU; cap VGPR at
// <=170 so all 3 stay resident.
__global__ __launch_bounds__(256, 3) void ssim_kernel(
    const float* __restrict__ x, const float* __restrict__ y,
    float* __restrict__ out)
{
    const int img  = blockIdx.z;
    const int lane = threadIdx.x;                       // 0..63
    const int wv   = threadIdx.y;                       // 0..3
    const int c0   = blockIdx.x * STRIPW;               // 0,256,512,768
    const int h0   = blockIdx.y * ROWS_PER_BLOCK + wv * RH;   // 0..480

    const int cb = c0 + lane * CW;                      // output col base
    const bool col_ok = (cb + CW - 1) < OW;             // cb <= 952
    const int cbl = col_ok ? cb : (OW - CW);            // clamped load base (952)

    const float* __restrict__ xi = x + (size_t)img * H * W;
    const float* __restrict__ yi = y + (size_t)img * H * W;
    float* __restrict__ oi = out + (size_t)img * OH * OW;

    const float inv9 = 1.0f / 9.0f;
    const float C1v = 1e-4f, C2v = 9e-4f;

    // loop-carried state (kk=0 entries uninitialized but unread: k>=2/k>=4 guards)
    float hx_m2[6], hx_m1[6], hy_m2[6], hy_m1[6];
    float xc_m1[6], yc_m1[6];
    float ha_m2[4], ha_m1[4], hb_m2[4], hb_m1[4], hc_m2[4], hc_m1[4];
    float mu_mx[6], mu_my[6];

    // rotating row buffers: A=row kb, B=row kb+1, C=row kb+2
    float4 Axa, Axb, Aya, Ayb;
    float4 Bxa, Bxb, Bya, Byb;
    float4 Cxa, Cxb, Cya, Cyb;
    LOADROW(0, Axa, Axb, Aya, Ayb)
    LOADROW(1, Bxa, Bxb, Bya, Byb)
    LOADROW(2, Cxa, Cxb, Cya, Cyb)

#pragma unroll 1
    for (int kk = 0; kk < KK; ++kk) {
        const int kb = 3 * kk;
        float hx0[6], hy0[6], hx1[6], hy1[6], hx2[6], hy2[6];
        float xc0[6], yc0[6], xc1[6], yc1[6], xc2[6], yc2[6];
        float ha0[4], hb0[4], hc0[4], ha1[4], hb1[4], hc1[4], ha2[4], hb2[4], hc2[4];
        float mu0x[6], mu0y[6], mu1x[6], mu1y[6], mu2x[6], mu2y[6];

        // phase consumes its buffer, then immediately re-issues it 3 rows
        // ahead — loads for rows kb+1..kb+5 overlap all remaining compute
        PHASE(kb + 0, Axa,Axb,Aya,Ayb, hx_m2,hy_m2, hx_m1,hy_m1, hx0,hy0,
              xc_m1,yc_m1, xc0,yc0,
              ha_m2,hb_m2,hc_m2, ha_m1,hb_m1,hc_m1, ha0,hb0,hc0,
              mu_mx,mu_my, mu0x,mu0y)
        LOADROW(kb + 3, Axa, Axb, Aya, Ayb)

        PHASE(kb + 1, Bxa,Bxb,Bya,Byb, hx_m1,hy_m1, hx0,hy0, hx1,hy1,
              xc0,yc0, xc1,yc1,
              ha_m1,hb_m1,hc_m1, ha0,hb0,hc0, ha1,hb1,hc1,
              mu0x,mu0y, mu1x,mu1y)
        LOADROW(kb + 4, Bxa, Bxb, Bya, Byb)

        PHASE(kb + 2, Cxa,Cxb,Cya,Cyb, hx0,hy0, hx1,hy1, hx2,hy2,
              xc1,yc1, xc2,yc2,
              ha0,hb0,hc0, ha1,hb1,hc1, ha2,hb2,hc2,
              mu1x,mu1y, mu2x,mu2y)
        LOADROW(kb + 5, Cxa, Cxb, Cya, Cyb)

        // carry to next body (coalescable phis — compile-time indices only)
#pragma unroll
        for (int q = 0; q < 6; ++q) {
            hx_m2[q] = hx1[q]; hx_m1[q] = hx2[q];
            hy_m2[q] = hy1[q]; hy_m1[q] = hy2[q];
            xc_m1[q] = xc2[q]; yc_m1[q] = yc2[q];
            mu_mx[q] = mu2x[q]; mu_my[q] = mu2y[q];
        }
#pragma unroll
        for (int w = 0; w < 4; ++w) {
            ha_m2[w] = ha1[w]; ha_m1[w] = ha2[w];
            hb_m2[w] = hb1[w]; hb_m1[w] = hb2[w];
            hc_m2[w] = hc1[w]; hc_m1[w] = hc2[w];
        }
    }
}

extern "C" void kernel_launch(void* const* d_in, const int* in_sizes, int n_in,
                              void* d_out, int out_size, void* d_ws, size_t ws_size,
                              hipStream_t stream) {
    const float* x = (const float*)d_in[0];
    const float* y = (const float*)d_in[1];
    float* out = (float*)d_out;

    dim3 grid((OW + STRIPW - 1) / STRIPW,                 // 4
              (OH + ROWS_PER_BLOCK - 1) / ROWS_PER_BLOCK, // 4
              NIMG);                                      // 48
    dim3 block(64, WAVES_PER_BLOCK, 1);
    ssim_kernel<<<grid, block, 0, stream>>>(x, y, out);
}

// Round 6
// 254.304 us; speedup vs baseline: 1.7890x; 1.7890x over previous
//
#include <hip/hip_runtime.h>

#define H 512
#define W 960
#define OH 508
#define OW 956
#define NIMG 48

#define RH 32                       // output rows per wave
#define WAVES_PER_BLOCK 4
#define ROWS_PER_BLOCK (RH * WAVES_PER_BLOCK)   // 128
#define CW 4                        // output cols per thread
#define STRIPW (64 * CW)            // 256 output cols per wave-strip
#define KK 12                       // 12 x 3-phase body = 36 input rows (compile-time)

typedef float f32x4 __attribute__((ext_vector_type(4)));

// Issue the 4 global loads for input row (h0+KV), clamped, into 4 named
// f32x4 (clang ext-vector) regs. Round-5 lesson: loop-carried HIP float4
// (union-based class) buffers were demoted to scratch (WRITE 92->528MB at
// VGPR=84 = demotion, not regalloc). Ext-vectors are first-class <4 x float>
// SSA values; loop-carried vector phis promote cleanly.
#define LOADROW(KV, XA,XB,YA,YB) \
{ \
    const int r_ = h0 + (KV); \
    const int rl_ = r_ < H ? r_ : (H - 1); \
    const f32x4* px_ = (const f32x4*)(xi + (size_t)rl_ * W + cbl); \
    const f32x4* py_ = (const f32x4*)(yi + (size_t)rl_ * W + cbl); \
    XA = px_[0]; XB = px_[1]; \
    YA = py_[0]; YB = py_[1]; \
}

// One pipeline phase: consume buffered input row (wave-local index KV),
// update histories. ALL array args are distinct named locals with
// compile-time indices only — rotation is SSA renaming (round-3 lesson).
#define PHASE(KV, XA,XB,YA,YB, HX2,HY2, HX1,HY1, HXW,HYW, XC1,YC1, XCW,YCW, \
              HA2,HB2,HC2, HA1,HB1,HC1, HAW,HBW,HCW, MIX,MIY, MOX,MOY) \
{ \
    const int k_ = (KV); \
    float xc_[8] = {XA[0], XA[1], XA[2], XA[3], XB[0], XB[1], XB[2], XB[3]}; \
    float yc_[8] = {YA[0], YA[1], YA[2], YA[3], YB[0], YB[1], YB[2], YB[3]}; \
    _Pragma("unroll") \
    for (int q = 0; q < 6; ++q) { \
        HXW[q] = xc_[q] + xc_[q + 1] + xc_[q + 2]; \
        HYW[q] = yc_[q] + yc_[q + 1] + yc_[q + 2]; \
        XCW[q] = xc_[q + 1]; \
        YCW[q] = yc_[q + 1]; \
    } \
    if (k_ >= 2) { \
        float a6_[6], b6_[6], c6_[6]; \
        _Pragma("unroll") \
        for (int q = 0; q < 6; ++q) { \
            MOX[q] = (HX2[q] + HX1[q] + HXW[q]) * inv9; \
            MOY[q] = (HY2[q] + HY1[q] + HYW[q]) * inv9; \
            float dx_ = XC1[q] - MOX[q]; \
            float dy_ = YC1[q] - MOY[q]; \
            a6_[q] = dx_ * dx_; \
            b6_[q] = dy_ * dy_; \
            c6_[q] = dx_ * dy_; \
        } \
        float ha_[4], hb_[4], hc_[4]; \
        _Pragma("unroll") \
        for (int w = 0; w < 4; ++w) { \
            ha_[w] = a6_[w] + a6_[w + 1] + a6_[w + 2]; \
            hb_[w] = b6_[w] + b6_[w + 1] + b6_[w + 2]; \
            hc_[w] = c6_[w] + c6_[w + 1] + c6_[w + 2]; \
        } \
        if (k_ >= 4) { \
            const int h_ = h0 + k_ - 4; \
            float ov_[4]; \
            _Pragma("unroll") \
            for (int w = 0; w < 4; ++w) { \
                float sigx_  = (HA2[w] + HA1[w] + ha_[w]) * inv9; \
                float sigy_  = (HB2[w] + HB1[w] + hb_[w]) * inv9; \
                float sigxy_ = (HC2[w] + HC1[w] + hc_[w]) * inv9; \
                float mx_ = MIX[w + 1]; \
                float my_ = MIY[w + 1]; \
                float n_ = (2.f * mx_ * my_ + C1v) * (2.f * sigxy_ + C2v); \
                float d_ = (mx_ * mx_ + my_ * my_ + C1v) * (sigx_ + sigy_ + C2v); \
                float v_ = 1.f - n_ * __builtin_amdgcn_rcpf(d_); \
                ov_[w] = fminf(fmaxf(v_, 0.f), 2.f); \
            } \
            if (col_ok && h_ < OH) { \
                f32x4 o_ = {ov_[0], ov_[1], ov_[2], ov_[3]}; \
                __builtin_nontemporal_store(o_, (f32x4*)(oi + (size_t)h_ * OW + cb)); \
            } \
        } \
        _Pragma("unroll") \
        for (int w = 0; w < 4; ++w) { \
            HAW[w] = ha_[w]; HBW[w] = hb_[w]; HCW[w] = hc_[w]; \
        } \
    } \
}

// Register-resident sliding-window SSIM, 3-phase hand-rotated pipeline with
// 3 rotating ext-vector row buffers (A/B/C) for deep per-wave load MLP.
// Thread = 4 output cols; wave = 256-col strip x 32 rows; no LDS, no barriers.
__global__ __launch_bounds__(256) void ssim_kernel(
    const float* __restrict__ x, const float* __restrict__ y,
    float* __restrict__ out)
{
    const int img  = blockIdx.z;
    const int lane = threadIdx.x;                       // 0..63
    const int wv   = threadIdx.y;                       // 0..3
    const int c0   = blockIdx.x * STRIPW;               // 0,256,512,768
    const int h0   = blockIdx.y * ROWS_PER_BLOCK + wv * RH;   // 0..480

    const int cb = c0 + lane * CW;                      // output col base
    const bool col_ok = (cb + CW - 1) < OW;             // cb <= 952
    const int cbl = col_ok ? cb : (OW - CW);            // clamped load base (952)

    const float* __restrict__ xi = x + (size_t)img * H * W;
    const float* __restrict__ yi = y + (size_t)img * H * W;
    float* __restrict__ oi = out + (size_t)img * OH * OW;

    const float inv9 = 1.0f / 9.0f;
    const float C1v = 1e-4f, C2v = 9e-4f;

    // loop-carried state (kk=0 entries uninitialized but unread: k>=2/k>=4 guards)
    float hx_m2[6], hx_m1[6], hy_m2[6], hy_m1[6];
    float xc_m1[6], yc_m1[6];
    float ha_m2[4], ha_m1[4], hb_m2[4], hb_m1[4], hc_m2[4], hc_m1[4];
    float mu_mx[6], mu_my[6];

    // rotating row buffers: A=row kb, B=row kb+1, C=row kb+2
    f32x4 Axa, Axb, Aya, Ayb;
    f32x4 Bxa, Bxb, Bya, Byb;
    f32x4 Cxa, Cxb, Cya, Cyb;
    LOADROW(0, Axa, Axb, Aya, Ayb)
    LOADROW(1, Bxa, Bxb, Bya, Byb)
    LOADROW(2, Cxa, Cxb, Cya, Cyb)

#pragma unroll 1
    for (int kk = 0; kk < KK; ++kk) {
        const int kb = 3 * kk;
        float hx0[6], hy0[6], hx1[6], hy1[6], hx2[6], hy2[6];
        float xc0[6], yc0[6], xc1[6], yc1[6], xc2[6], yc2[6];
        float ha0[4], hb0[4], hc0[4], ha1[4], hb1[4], hc1[4], ha2[4], hb2[4], hc2[4];
        float mu0x[6], mu0y[6], mu1x[6], mu1y[6], mu2x[6], mu2y[6];

        // phase consumes its buffer, then immediately re-issues it 3 rows
        // ahead — loads for rows kb+1..kb+5 overlap all remaining compute
        PHASE(kb + 0, Axa,Axb,Aya,Ayb, hx_m2,hy_m2, hx_m1,hy_m1, hx0,hy0,
              xc_m1,yc_m1, xc0,yc0,
              ha_m2,hb_m2,hc_m2, ha_m1,hb_m1,hc_m1, ha0,hb0,hc0,
              mu_mx,mu_my, mu0x,mu0y)
        LOADROW(kb + 3, Axa, Axb, Aya, Ayb)

        PHASE(kb + 1, Bxa,Bxb,Bya,Byb, hx_m1,hy_m1, hx0,hy0, hx1,hy1,
              xc0,yc0, xc1,yc1,
              ha_m1,hb_m1,hc_m1, ha0,hb0,hc0, ha1,hb1,hc1,
              mu0x,mu0y, mu1x,mu1y)
        LOADROW(kb + 4, Bxa, Bxb, Bya, Byb)

        PHASE(kb + 2, Cxa,Cxb,Cya,Cyb, hx0,hy0, hx1,hy1, hx2,hy2,
              xc1,yc1, xc2,yc2,
              ha0,hb0,hc0, ha1,hb1,hc1, ha2,hb2,hc2,
              mu1x,mu1y, mu2x,mu2y)
        LOADROW(kb + 5, Cxa, Cxb, Cya, Cyb)

        // carry to next body (coalescable phis — compile-time indices only)
#pragma unroll
        for (int q = 0; q < 6; ++q) {
            hx_m2[q] = hx1[q]; hx_m1[q] = hx2[q];
            hy_m2[q] = hy1[q]; hy_m1[q] = hy2[q];
            xc_m1[q] = xc2[q]; yc_m1[q] = yc2[q];
            mu_mx[q] = mu2x[q]; mu_my[q] = mu2y[q];
        }
#pragma unroll
        for (int w = 0; w < 4; ++w) {
            ha_m2[w] = ha1[w]; ha_m1[w] = ha2[w];
            hb_m2[w] = hb1[w]; hb_m1[w] = hb2[w];
            hc_m2[w] = hc1[w]; hc_m1[w] = hc2[w];
        }
    }
}

extern "C" void kernel_launch(void* const* d_in, const int* in_sizes, int n_in,
                              void* d_out, int out_size, void* d_ws, size_t ws_size,
                              hipStream_t stream) {
    const float* x = (const float*)d_in[0];
    const float* y = (const float*)d_in[1];
    float* out = (float*)d_out;

    dim3 grid((OW + STRIPW - 1) / STRIPW,                 // 4
              (OH + ROWS_PER_BLOCK - 1) / ROWS_PER_BLOCK, // 4
              NIMG);                                      // 48
    dim3 block(64, WAVES_PER_BLOCK, 1);
    ssim_kernel<<<grid, block, 0, stream>>>(x, y, out);
}